// Round 5
// baseline (134.371 us; speedup 1.0000x reference)
//
#include <hip/hip_runtime.h>
#include <hip/hip_bf16.h>
#include <hip/hip_cooperative_groups.h>

namespace cg = cooperative_groups;

namespace {

constexpr int GRIDC = 16;                    // 16^3 cells, cell = 0.0625 > max radius 0.0601
constexpr int NCELL = GRIDC * GRIDC * GRIDC; // 4096
constexpr int CAP   = 48;                    // per-cell list capacity (avg load ~5)
constexpr int RECF  = 16;                    // floats per record (64 B, cacheline-aligned)
constexpr int PREPB = 8;                     // prep blocks (>= ng/256)

__device__ __forceinline__ float sigmoid_(float v) {
    if (v >= 0.0f) { float e = expf(-v); return 1.0f / (1.0f + e); }
    float e = expf(v); return e / (1.0f + e);
}

} // namespace

// ---- cooperative: zero counts + detect layout | grid.sync | preprocess+insert
__global__ void __launch_bounds__(256)
VEG_prep(const unsigned char* __restrict__ vg,
         const float* __restrict__ xyz, const float* __restrict__ sraw,
         const float* __restrict__ rraw, const float* __restrict__ wraw,
         const float* __restrict__ vraw,
         float* __restrict__ recs, int* __restrict__ counts,
         int* __restrict__ mode_p, int ng) {
    __shared__ int sf1, sf3;
    int tid = blockIdx.x * 256 + threadIdx.x;

    // phase 1a: zero the cell counters (2048 threads x 2)
    for (int c = tid; c < NCELL; c += PREPB * 256) counts[c] = 0;

    // phase 1b: block 0 detects bool-buffer layout from first 4096 bytes
    // mode 0: uint8 (numpy bool), 1: int32, 2: float32
    if (threadIdx.x == 0) { sf1 = 0; sf3 = 0; }
    __syncthreads();
    if (blockIdx.x == 0) {
        uint4 v = ((const uint4*)vg)[threadIdx.x];       // 256*16 = 4096 B
        unsigned m = v.x | v.y | v.z | v.w;
        if (m & 0x0000FF00u) atomicOr(&sf1, 1);          // byte%4==1 -> uint8 layout
        if (m & 0xFF000000u) atomicOr(&sf3, 1);          // byte%4==3 -> float32 (or uint8)
    }
    __syncthreads();
    if (blockIdx.x == 0 && threadIdx.x == 0) *mode_p = sf1 ? 0 : (sf3 ? 2 : 1);

    cg::this_grid().sync();

    // phase 2: per-gaussian preprocess + inline-record insertion
    int g = tid;
    if (g >= ng) return;

    float s0 = expf(sraw[g * 3 + 0]);
    float s1 = expf(sraw[g * 3 + 1]);
    float s2 = expf(sraw[g * 3 + 2]);
    float r  = sqrtf(s0 * s0 + s1 * s1 + s2 * s2) + 1e-8f;
    float rs = 0.02f * tanhf(r / 0.02f);
    float fsc = rs / r;
    s0 *= fsc; s1 *= fsc; s2 *= fsc;

    float q0 = rraw[g * 4 + 0], q1 = rraw[g * 4 + 1];
    float q2 = rraw[g * 4 + 2], q3 = rraw[g * 4 + 3];
    float qn = fmaxf(sqrtf(q0 * q0 + q1 * q1 + q2 * q2 + q3 * q3), 1e-12f);
    float inv = 1.0f / qn;
    float rr = q0 * inv, qx = q1 * inv, qy = q2 * inv, qz = q3 * inv;
    float R00 = 1.0f - 2.0f * (qy * qy + qz * qz);
    float R01 = 2.0f * (qx * qy - rr * qz);
    float R02 = 2.0f * (qx * qz + rr * qy);
    float R10 = 2.0f * (qx * qy + rr * qz);
    float R11 = 1.0f - 2.0f * (qx * qx + qz * qz);
    float R12 = 2.0f * (qy * qz - rr * qx);
    float R20 = 2.0f * (qx * qz - rr * qy);
    float R21 = 2.0f * (qy * qz + rr * qx);
    float R22 = 1.0f - 2.0f * (qx * qx + qy * qy);

    float i0 = 1.0f / (s0 * s0), i1 = 1.0f / (s1 * s1), i2 = 1.0f / (s2 * s2);
    float4 rA = make_float4(xyz[g * 3 + 0], xyz[g * 3 + 1], xyz[g * 3 + 2],
                            R00 * R00 * i0 + R01 * R01 * i1 + R02 * R02 * i2);
    float4 rB = make_float4(R10 * R10 * i0 + R11 * R11 * i1 + R12 * R12 * i2,
                            R20 * R20 * i0 + R21 * R21 * i1 + R22 * R22 * i2,
                            R00 * R10 * i0 + R01 * R11 * i1 + R02 * R12 * i2,
                            R00 * R20 * i0 + R01 * R21 * i1 + R02 * R22 * i2);
    float w = sigmoid_(wraw[g]);
    float v = sigmoid_(vraw[g]);
    float4 rC = make_float4(R10 * R20 * i0 + R11 * R21 * i1 + R12 * R22 * i2,
                            w, w * v, 0.0f);

    float rad = 3.0f * fmaxf(fmaxf(s0, s1), s2);   // qd<=9 => |d|<=3*max(s)
    rad = rad * 1.001f + 1e-6f;
    float cx = rA.x, cy = rA.y, cz = rA.z;

    int xlo = max(0, (int)floorf((cx - rad) * (float)GRIDC));
    int xhi = min(GRIDC - 1, (int)floorf((cx + rad) * (float)GRIDC));
    int ylo = max(0, (int)floorf((cy - rad) * (float)GRIDC));
    int yhi = min(GRIDC - 1, (int)floorf((cy + rad) * (float)GRIDC));
    int zlo = max(0, (int)floorf((cz - rad) * (float)GRIDC));
    int zhi = min(GRIDC - 1, (int)floorf((cz + rad) * (float)GRIDC));
    for (int zz = zlo; zz <= zhi; ++zz)
        for (int yy = ylo; yy <= yhi; ++yy)
            for (int xx = xlo; xx <= xhi; ++xx) {
                int cell = (zz * GRIDC + yy) * GRIDC + xx;
                int slot = atomicAdd(&counts[cell], 1);
                if (slot < CAP) {
                    float4* o = (float4*)(recs + ((size_t)cell * CAP + slot) * RECF);
                    o[0] = rA; o[1] = rB; o[2] = rC;
                }
            }
}

// ---- main: one thread per point; x staged via LDS; inline per-cell records
__global__ void __launch_bounds__(256)
VEG_splat(const float* __restrict__ x, const float* __restrict__ recs,
          const int* __restrict__ counts,
          const void* __restrict__ valid, const int* __restrict__ mode_p,
          float* __restrict__ out, int npts) {
    __shared__ float shx[768];
    int base = blockIdx.x * 256;
    int nrem = npts - base;
    if (nrem >= 256) {
        if (threadIdx.x < 192)
            ((float4*)shx)[threadIdx.x] = ((const float4*)(x + (size_t)base * 3))[threadIdx.x];
    } else {
        for (int j = threadIdx.x; j < nrem * 3; j += 256)
            shx[j] = x[(size_t)base * 3 + j];
    }
    __syncthreads();

    int i = base + threadIdx.x;
    if (i >= npts) return;

    float px = (shx[threadIdx.x * 3 + 0] + 1.0f) * 0.5f;
    float py = (shx[threadIdx.x * 3 + 1] + 1.0f) * 0.5f;
    float pz = (shx[threadIdx.x * 3 + 2] + 1.0f) * 0.5f;

    // issue the cell-count load first (longest dependent chain)
    int cx = min(GRIDC - 1, (int)(px * (float)GRIDC));
    int cy = min(GRIDC - 1, (int)(py * (float)GRIDC));
    int cz = min(GRIDC - 1, (int)(pz * (float)GRIDC));
    int cell = (cz * GRIDC + cy) * GRIDC + cx;
    int cnt = counts[cell];
    const float4* rec = (const float4*)(recs + (size_t)cell * CAP * RECF);

    int ix = min(99, max(0, (int)rintf(px * 99.0f)));   // rintf = round half-to-even
    int iy = min(99, max(0, (int)rintf(py * 99.0f)));
    int iz = min(99, max(0, (int)rintf(pz * 99.0f)));
    int flat = iz * 10000 + iy * 100 + ix;

    int mode = *mode_p;
    bool vb;
    if (mode == 0)      vb = ((const unsigned char*)valid)[flat] != 0;
    else if (mode == 1) vb = ((const int*)valid)[flat] != 0;
    else                vb = ((const float*)valid)[flat] != 0.0f;

    cnt = (cnt < 0) ? 0 : min(cnt, CAP);   // defensive vs uninitialized counts
    float den = 0.0f, num = 0.0f;
#pragma unroll 2
    for (int j = 0; j < cnt; ++j) {
        float4 A = rec[j * 4 + 0], B = rec[j * 4 + 1], C = rec[j * 4 + 2];
        float dx = px - A.x, dy = py - A.y, dz = pz - A.z;
        float qd = A.w * dx * dx + B.x * dy * dy + B.y * dz * dz +
                   2.0f * (B.z * dx * dy + B.w * dx * dz + C.x * dy * dz);
        if (qd <= 9.0f) {
            float e = __expf(-0.5f * qd);
            den = fmaf(C.y, e, den);
            num = fmaf(C.z, e, num);
        }
    }
    float y = (den > 0.0f) ? (num / den) : -1.0f;
    out[i] = vb ? y : 0.0f;
}

// ---- fallback: brute force (only if ws_size is absurdly small) ------------
__global__ void VEG_detect(const unsigned char* vg, int* mode) {
    __shared__ int f1, f3;
    if (threadIdx.x == 0) { f1 = 0; f3 = 0; }
    __syncthreads();
    for (int i = threadIdx.x; i < 4096; i += blockDim.x) {
        unsigned char b = vg[i];
        if (b) {
            int m = i & 3;
            if (m == 1) atomicOr(&f1, 1);
            if (m == 3) atomicOr(&f3, 1);
        }
    }
    __syncthreads();
    if (threadIdx.x == 0) *mode = f1 ? 0 : (f3 ? 2 : 1);
}

__global__ void __launch_bounds__(256)
VEG_brute(const float* __restrict__ x, const float* __restrict__ xyz,
          const float* __restrict__ sraw, const float* __restrict__ rraw,
          const float* __restrict__ wraw, const float* __restrict__ vraw,
          const void* __restrict__ valid, const int* __restrict__ mode_p,
          float* __restrict__ out, int npts, int ng) {
    __shared__ float sh[256 * 12];
    int i = blockIdx.x * blockDim.x + threadIdx.x;
    bool inb = i < npts;
    float px = 0, py = 0, pz = 0; int flat = 0;
    if (inb) {
        px = (x[i * 3 + 0] + 1.0f) * 0.5f;
        py = (x[i * 3 + 1] + 1.0f) * 0.5f;
        pz = (x[i * 3 + 2] + 1.0f) * 0.5f;
        int ix = min(99, max(0, (int)rintf(px * 99.0f)));
        int iy = min(99, max(0, (int)rintf(py * 99.0f)));
        int iz = min(99, max(0, (int)rintf(pz * 99.0f)));
        flat = iz * 10000 + iy * 100 + ix;
    }
    float den = 0.0f, num = 0.0f;
    for (int base = 0; base < ng; base += 256) {
        __syncthreads();
        int g = base + threadIdx.x;
        if (g < ng) {
            float s0 = expf(sraw[g * 3 + 0]);
            float s1 = expf(sraw[g * 3 + 1]);
            float s2 = expf(sraw[g * 3 + 2]);
            float r  = sqrtf(s0 * s0 + s1 * s1 + s2 * s2) + 1e-8f;
            float rs = 0.02f * tanhf(r / 0.02f);
            float fsc = rs / r;
            s0 *= fsc; s1 *= fsc; s2 *= fsc;
            float q0 = rraw[g * 4 + 0], q1 = rraw[g * 4 + 1];
            float q2 = rraw[g * 4 + 2], q3 = rraw[g * 4 + 3];
            float qn = fmaxf(sqrtf(q0 * q0 + q1 * q1 + q2 * q2 + q3 * q3), 1e-12f);
            float inv = 1.0f / qn;
            float rr = q0 * inv, qx = q1 * inv, qy = q2 * inv, qz = q3 * inv;
            float R00 = 1.0f - 2.0f * (qy * qy + qz * qz);
            float R01 = 2.0f * (qx * qy - rr * qz);
            float R02 = 2.0f * (qx * qz + rr * qy);
            float R10 = 2.0f * (qx * qy + rr * qz);
            float R11 = 1.0f - 2.0f * (qx * qx + qz * qz);
            float R12 = 2.0f * (qy * qz - rr * qx);
            float R20 = 2.0f * (qx * qz - rr * qy);
            float R21 = 2.0f * (qy * qz + rr * qx);
            float R22 = 1.0f - 2.0f * (qx * qx + qy * qy);
            float i0 = 1.0f / (s0 * s0), i1 = 1.0f / (s1 * s1), i2 = 1.0f / (s2 * s2);
            float* o = sh + threadIdx.x * 12;
            o[0] = xyz[g * 3 + 0]; o[1] = xyz[g * 3 + 1]; o[2] = xyz[g * 3 + 2];
            o[3] = R00 * R00 * i0 + R01 * R01 * i1 + R02 * R02 * i2;
            o[4] = R10 * R10 * i0 + R11 * R11 * i1 + R12 * R12 * i2;
            o[5] = R20 * R20 * i0 + R21 * R21 * i1 + R22 * R22 * i2;
            o[6] = R00 * R10 * i0 + R01 * R11 * i1 + R02 * R12 * i2;
            o[7] = R00 * R20 * i0 + R01 * R21 * i1 + R02 * R22 * i2;
            o[8] = R10 * R20 * i0 + R11 * R21 * i1 + R12 * R22 * i2;
            float w = sigmoid_(wraw[g]);
            float v = sigmoid_(vraw[g]);
            o[9] = w; o[10] = w * v; o[11] = 0.0f;
        }
        __syncthreads();
        int tile = min(256, ng - base);
        if (inb) {
            for (int j = 0; j < tile; ++j) {
                const float* o = sh + j * 12;
                float dx = px - o[0], dy = py - o[1], dz = pz - o[2];
                float qd = o[3] * dx * dx + o[4] * dy * dy + o[5] * dz * dz +
                           2.0f * (o[6] * dx * dy + o[7] * dx * dz + o[8] * dy * dz);
                if (qd <= 9.0f) {
                    float e = expf(-0.5f * qd);
                    den = fmaf(o[9], e, den);
                    num = fmaf(o[10], e, num);
                }
            }
        }
    }
    if (inb) {
        int mode = *mode_p;
        bool vb;
        if (mode == 0)      vb = ((const unsigned char*)valid)[flat] != 0;
        else if (mode == 1) vb = ((const int*)valid)[flat] != 0;
        else                vb = ((const float*)valid)[flat] != 0.0f;
        float y = (den > 0.0f) ? (num / den) : -1.0f;
        out[i] = vb ? y : 0.0f;
    }
}

extern "C" void kernel_launch(void* const* d_in, const int* in_sizes, int n_in,
                              void* d_out, int out_size, void* d_ws, size_t ws_size,
                              hipStream_t stream) {
    const float* x    = (const float*)d_in[0];
    const float* xyz  = (const float*)d_in[1];
    const float* sraw = (const float*)d_in[2];
    const float* rraw = (const float*)d_in[3];
    const float* wraw = (const float*)d_in[4];
    const float* vraw = (const float*)d_in[5];
    const void*  valid = d_in[6];
    float* out = (float*)d_out;

    int npts = in_sizes[0] / 3;
    int ng   = in_sizes[4];

    char* ws = (char*)d_ws;
    size_t mode_off   = 0;
    size_t counts_off = 256;
    size_t recs_off   = counts_off + (size_t)NCELL * sizeof(int);
    recs_off = (recs_off + 255) & ~(size_t)255;
    size_t total = recs_off + (size_t)NCELL * CAP * RECF * sizeof(float);

    int* mode = (int*)(ws + mode_off);

    if (ws_size >= total && ng <= PREPB * 256) {
        int*   counts = (int*)(ws + counts_off);
        float* recs   = (float*)(ws + recs_off);
        const unsigned char* vg = (const unsigned char*)valid;
        void* args[] = {(void*)&vg, (void*)&xyz, (void*)&sraw, (void*)&rraw,
                        (void*)&wraw, (void*)&vraw, (void*)&recs, (void*)&counts,
                        (void*)&mode, (void*)&ng};
        hipLaunchCooperativeKernel((const void*)VEG_prep, dim3(PREPB), dim3(256),
                                   args, 0, stream);
        VEG_splat<<<(npts + 255) / 256, 256, 0, stream>>>(x, recs, counts,
                                                          valid, mode, out, npts);
    } else {
        VEG_detect<<<1, 256, 0, stream>>>((const unsigned char*)valid, mode);
        VEG_brute<<<(npts + 255) / 256, 256, 0, stream>>>(x, xyz, sraw, rraw, wraw,
                                                          vraw, valid, mode, out,
                                                          npts, ng);
    }
}

// Round 7
// 120.065 us; speedup vs baseline: 1.1192x; 1.1192x over previous
//
#include <hip/hip_runtime.h>
#include <hip/hip_bf16.h>

namespace {

constexpr int GRIDC = 16;                    // 16^3 cells, cell = 0.0625 > max radius 0.0601
constexpr int NCELL = GRIDC * GRIDC * GRIDC; // 4096
constexpr int CAP   = 48;                    // per-cell list capacity (avg load ~5)
constexpr int RECF  = 16;                    // floats per record (64 B, cacheline-aligned)
constexpr int PREPB = 8;                     // setup blocks; each owns NCELL/PREPB cells
constexpr int CPB   = NCELL / PREPB;         // 512 cells per block

__device__ __forceinline__ float sigmoid_(float v) {
    if (v >= 0.0f) { float e = expf(-v); return 1.0f / (1.0f + e); }
    float e = expf(v); return e / (1.0f + e);
}

// ---- setup: 8 blocks, each owns 512 cells; scans ALL gaussians; LDS counters
//      (no global atomics, no pre-zero, no grid sync). Block 0 also detects
//      the bool-buffer layout: mode 0=uint8, 1=int32, 2=float32.
__global__ void __launch_bounds__(256)
VEG_setup(const unsigned char* __restrict__ vg,
          const float* __restrict__ xyz, const float* __restrict__ sraw,
          const float* __restrict__ rraw, const float* __restrict__ wraw,
          const float* __restrict__ vraw,
          float* __restrict__ recs, int* __restrict__ counts,
          int* __restrict__ mode_p, int ng) {
    __shared__ int scount[CPB];
    __shared__ int sf1, sf3;
    if (threadIdx.x == 0) { sf1 = 0; sf3 = 0; }
    for (int c = threadIdx.x; c < CPB; c += 256) scount[c] = 0;
    __syncthreads();

    if (blockIdx.x == 0) {
        uint4 v = ((const uint4*)vg)[threadIdx.x];       // 256*16 = 4096 B scanned
        unsigned m = v.x | v.y | v.z | v.w;
        if (m & 0x0000FF00u) atomicOr(&sf1, 1);          // byte%4==1 -> uint8 layout
        if (m & 0xFF000000u) atomicOr(&sf3, 1);          // byte%4==3 -> float32 (or uint8)
    }

    int cellbase = blockIdx.x * CPB;
    for (int g = threadIdx.x; g < ng; g += 256) {
        float s0 = expf(sraw[g * 3 + 0]);
        float s1 = expf(sraw[g * 3 + 1]);
        float s2 = expf(sraw[g * 3 + 2]);
        float r  = sqrtf(s0 * s0 + s1 * s1 + s2 * s2) + 1e-8f;
        float rs = 0.02f * tanhf(r / 0.02f);
        float fsc = rs / r;
        s0 *= fsc; s1 *= fsc; s2 *= fsc;

        float rad = 3.0f * fmaxf(fmaxf(s0, s1), s2);     // qd<=9 => |d|<=3*max(s)
        rad = rad * 1.001f + 1e-6f;
        float cx = xyz[g * 3 + 0], cy = xyz[g * 3 + 1], cz = xyz[g * 3 + 2];

        // cell overlap box; skip early if it misses this block's cell slab
        int xlo = max(0, (int)floorf((cx - rad) * (float)GRIDC));
        int xhi = min(GRIDC - 1, (int)floorf((cx + rad) * (float)GRIDC));
        int ylo = max(0, (int)floorf((cy - rad) * (float)GRIDC));
        int yhi = min(GRIDC - 1, (int)floorf((cy + rad) * (float)GRIDC));
        int zlo = max(0, (int)floorf((cz - rad) * (float)GRIDC));
        int zhi = min(GRIDC - 1, (int)floorf((cz + rad) * (float)GRIDC));
        int cmin = (zlo * GRIDC + ylo) * GRIDC + xlo;
        int cmax = (zhi * GRIDC + yhi) * GRIDC + xhi;
        if (cmax < cellbase || cmin >= cellbase + CPB) continue;

        float q0 = rraw[g * 4 + 0], q1 = rraw[g * 4 + 1];
        float q2 = rraw[g * 4 + 2], q3 = rraw[g * 4 + 3];
        float qn = fmaxf(sqrtf(q0 * q0 + q1 * q1 + q2 * q2 + q3 * q3), 1e-12f);
        float inv = 1.0f / qn;
        float rr = q0 * inv, qx = q1 * inv, qy = q2 * inv, qz = q3 * inv;
        float R00 = 1.0f - 2.0f * (qy * qy + qz * qz);
        float R01 = 2.0f * (qx * qy - rr * qz);
        float R02 = 2.0f * (qx * qz + rr * qy);
        float R10 = 2.0f * (qx * qy + rr * qz);
        float R11 = 1.0f - 2.0f * (qx * qx + qz * qz);
        float R12 = 2.0f * (qy * qz - rr * qx);
        float R20 = 2.0f * (qx * qz - rr * qy);
        float R21 = 2.0f * (qy * qz + rr * qx);
        float R22 = 1.0f - 2.0f * (qx * qx + qy * qy);

        float i0 = 1.0f / (s0 * s0), i1 = 1.0f / (s1 * s1), i2 = 1.0f / (s2 * s2);
        float4 rA = make_float4(cx, cy, cz,
                                R00 * R00 * i0 + R01 * R01 * i1 + R02 * R02 * i2);
        float4 rB = make_float4(R10 * R10 * i0 + R11 * R11 * i1 + R12 * R12 * i2,
                                R20 * R20 * i0 + R21 * R21 * i1 + R22 * R22 * i2,
                                R00 * R10 * i0 + R01 * R11 * i1 + R02 * R12 * i2,
                                R00 * R20 * i0 + R01 * R21 * i1 + R02 * R22 * i2);
        float w = sigmoid_(wraw[g]);
        float v = sigmoid_(vraw[g]);
        float4 rC = make_float4(R10 * R20 * i0 + R11 * R21 * i1 + R12 * R22 * i2,
                                w, w * v, 0.0f);

        for (int zz = zlo; zz <= zhi; ++zz)
            for (int yy = ylo; yy <= yhi; ++yy)
                for (int xx = xlo; xx <= xhi; ++xx) {
                    int cell  = (zz * GRIDC + yy) * GRIDC + xx;
                    int local = cell - cellbase;
                    if ((unsigned)local < (unsigned)CPB) {
                        int slot = atomicAdd(&scount[local], 1);
                        if (slot < CAP) {
                            float4* o = (float4*)(recs +
                                        ((size_t)cell * CAP + slot) * RECF);
                            o[0] = rA; o[1] = rB; o[2] = rC;
                        }
                    }
                }
    }
    __syncthreads();
    for (int c = threadIdx.x; c < CPB; c += 256) counts[cellbase + c] = scount[c];
    if (blockIdx.x == 0 && threadIdx.x == 0) *mode_p = sf1 ? 0 : (sf3 ? 2 : 1);
}

// ---- main: one thread per point; x staged via LDS; inline per-cell records
__global__ void __launch_bounds__(256)
VEG_splat(const float* __restrict__ x, const float* __restrict__ recs,
          const int* __restrict__ counts,
          const void* __restrict__ valid, const int* __restrict__ mode_p,
          float* __restrict__ out, int npts) {
    __shared__ float shx[768];
    int base = blockIdx.x * 256;
    int nrem = npts - base;
    if (nrem >= 256) {
        if (threadIdx.x < 192)
            ((float4*)shx)[threadIdx.x] = ((const float4*)(x + (size_t)base * 3))[threadIdx.x];
    } else {
        for (int j = threadIdx.x; j < nrem * 3; j += 256)
            shx[j] = x[(size_t)base * 3 + j];
    }
    __syncthreads();

    int i = base + threadIdx.x;
    if (i >= npts) return;

    float px = (shx[threadIdx.x * 3 + 0] + 1.0f) * 0.5f;
    float py = (shx[threadIdx.x * 3 + 1] + 1.0f) * 0.5f;
    float pz = (shx[threadIdx.x * 3 + 2] + 1.0f) * 0.5f;

    // issue the cell-count load first (longest dependent chain)
    int cx = min(GRIDC - 1, (int)(px * (float)GRIDC));
    int cy = min(GRIDC - 1, (int)(py * (float)GRIDC));
    int cz = min(GRIDC - 1, (int)(pz * (float)GRIDC));
    int cell = (cz * GRIDC + cy) * GRIDC + cx;
    int cnt = counts[cell];
    const float4* rec = (const float4*)(recs + (size_t)cell * CAP * RECF);

    int ix = min(99, max(0, (int)rintf(px * 99.0f)));   // rintf = round half-to-even
    int iy = min(99, max(0, (int)rintf(py * 99.0f)));
    int iz = min(99, max(0, (int)rintf(pz * 99.0f)));
    int flat = iz * 10000 + iy * 100 + ix;

    int mode = *mode_p;
    bool vb;
    if (mode == 0)      vb = ((const unsigned char*)valid)[flat] != 0;
    else if (mode == 1) vb = ((const int*)valid)[flat] != 0;
    else                vb = ((const float*)valid)[flat] != 0.0f;

    cnt = (cnt < 0) ? 0 : min(cnt, CAP);
    float den = 0.0f, num = 0.0f;
#pragma unroll 2
    for (int j = 0; j < cnt; ++j) {
        float4 A = rec[j * 4 + 0], B = rec[j * 4 + 1], C = rec[j * 4 + 2];
        float dx = px - A.x, dy = py - A.y, dz = pz - A.z;
        float qd = A.w * dx * dx + B.x * dy * dy + B.y * dz * dz +
                   2.0f * (B.z * dx * dy + B.w * dx * dz + C.x * dy * dz);
        if (qd <= 9.0f) {
            float e = __expf(-0.5f * qd);
            den = fmaf(C.y, e, den);
            num = fmaf(C.z, e, num);
        }
    }
    float y = (den > 0.0f) ? (num / den) : -1.0f;
    out[i] = vb ? y : 0.0f;
}

// ---- fallback: brute force (only if ws_size is absurdly small) ------------
__global__ void VEG_detect(const unsigned char* vg, int* mode) {
    __shared__ int f1, f3;
    if (threadIdx.x == 0) { f1 = 0; f3 = 0; }
    __syncthreads();
    for (int i = threadIdx.x; i < 4096; i += blockDim.x) {
        unsigned char b = vg[i];
        if (b) {
            int m = i & 3;
            if (m == 1) atomicOr(&f1, 1);
            if (m == 3) atomicOr(&f3, 1);
        }
    }
    __syncthreads();
    if (threadIdx.x == 0) *mode = f1 ? 0 : (f3 ? 2 : 1);
}

__global__ void __launch_bounds__(256)
VEG_brute(const float* __restrict__ x, const float* __restrict__ xyz,
          const float* __restrict__ sraw, const float* __restrict__ rraw,
          const float* __restrict__ wraw, const float* __restrict__ vraw,
          const void* __restrict__ valid, const int* __restrict__ mode_p,
          float* __restrict__ out, int npts, int ng) {
    __shared__ float sh[256 * 12];
    int i = blockIdx.x * blockDim.x + threadIdx.x;
    bool inb = i < npts;
    float px = 0, py = 0, pz = 0; int flat = 0;
    if (inb) {
        px = (x[i * 3 + 0] + 1.0f) * 0.5f;
        py = (x[i * 3 + 1] + 1.0f) * 0.5f;
        pz = (x[i * 3 + 2] + 1.0f) * 0.5f;
        int ix = min(99, max(0, (int)rintf(px * 99.0f)));
        int iy = min(99, max(0, (int)rintf(py * 99.0f)));
        int iz = min(99, max(0, (int)rintf(pz * 99.0f)));
        flat = iz * 10000 + iy * 100 + ix;
    }
    float den = 0.0f, num = 0.0f;
    for (int base = 0; base < ng; base += 256) {
        __syncthreads();
        int g = base + threadIdx.x;
        if (g < ng) {
            float s0 = expf(sraw[g * 3 + 0]);
            float s1 = expf(sraw[g * 3 + 1]);
            float s2 = expf(sraw[g * 3 + 2]);
            float r  = sqrtf(s0 * s0 + s1 * s1 + s2 * s2) + 1e-8f;
            float rs = 0.02f * tanhf(r / 0.02f);
            float fsc = rs / r;
            s0 *= fsc; s1 *= fsc; s2 *= fsc;
            float q0 = rraw[g * 4 + 0], q1 = rraw[g * 4 + 1];
            float q2 = rraw[g * 4 + 2], q3 = rraw[g * 4 + 3];
            float qn = fmaxf(sqrtf(q0 * q0 + q1 * q1 + q2 * q2 + q3 * q3), 1e-12f);
            float inv = 1.0f / qn;
            float rr = q0 * inv, qx = q1 * inv, qy = q2 * inv, qz = q3 * inv;
            float R00 = 1.0f - 2.0f * (qy * qy + qz * qz);
            float R01 = 2.0f * (qx * qy - rr * qz);
            float R02 = 2.0f * (qx * qz + rr * qy);
            float R10 = 2.0f * (qx * qy + rr * qz);
            float R11 = 1.0f - 2.0f * (qx * qx + qz * qz);
            float R12 = 2.0f * (qy * qz - rr * qx);
            float R20 = 2.0f * (qx * qz - rr * qy);
            float R21 = 2.0f * (qy * qz + rr * qx);
            float R22 = 1.0f - 2.0f * (qx * qx + qy * qy);
            float i0 = 1.0f / (s0 * s0), i1 = 1.0f / (s1 * s1), i2 = 1.0f / (s2 * s2);
            float* o = sh + threadIdx.x * 12;
            o[0] = xyz[g * 3 + 0]; o[1] = xyz[g * 3 + 1]; o[2] = xyz[g * 3 + 2];
            o[3] = R00 * R00 * i0 + R01 * R01 * i1 + R02 * R02 * i2;
            o[4] = R10 * R10 * i0 + R11 * R11 * i1 + R12 * R12 * i2;
            o[5] = R20 * R20 * i0 + R21 * R21 * i1 + R22 * R22 * i2;
            o[6] = R00 * R10 * i0 + R01 * R11 * i1 + R02 * R12 * i2;
            o[7] = R00 * R20 * i0 + R01 * R21 * i1 + R02 * R22 * i2;
            o[8] = R10 * R20 * i0 + R11 * R21 * i1 + R12 * R22 * i2;
            float w = sigmoid_(wraw[g]);
            float v = sigmoid_(vraw[g]);
            o[9] = w; o[10] = w * v; o[11] = 0.0f;
        }
        __syncthreads();
        int tile = min(256, ng - base);
        if (inb) {
            for (int j = 0; j < tile; ++j) {
                const float* o = sh + j * 12;
                float dx = px - o[0], dy = py - o[1], dz = pz - o[2];
                float qd = o[3] * dx * dx + o[4] * dy * dy + o[5] * dz * dz +
                           2.0f * (o[6] * dx * dy + o[7] * dx * dz + o[8] * dy * dz);
                if (qd <= 9.0f) {
                    float e = expf(-0.5f * qd);
                    den = fmaf(o[9], e, den);
                    num = fmaf(o[10], e, num);
                }
            }
        }
    }
    if (inb) {
        int mode = *mode_p;
        bool vb;
        if (mode == 0)      vb = ((const unsigned char*)valid)[flat] != 0;
        else if (mode == 1) vb = ((const int*)valid)[flat] != 0;
        else                vb = ((const float*)valid)[flat] != 0.0f;
        float y = (den > 0.0f) ? (num / den) : -1.0f;
        out[i] = vb ? y : 0.0f;
    }
}

} // namespace

extern "C" void kernel_launch(void* const* d_in, const int* in_sizes, int n_in,
                              void* d_out, int out_size, void* d_ws, size_t ws_size,
                              hipStream_t stream) {
    const float* x    = (const float*)d_in[0];
    const float* xyz  = (const float*)d_in[1];
    const float* sraw = (const float*)d_in[2];
    const float* rraw = (const float*)d_in[3];
    const float* wraw = (const float*)d_in[4];
    const float* vraw = (const float*)d_in[5];
    const void*  valid = d_in[6];
    float* out = (float*)d_out;

    int npts = in_sizes[0] / 3;
    int ng   = in_sizes[4];

    char* ws = (char*)d_ws;
    size_t mode_off   = 0;
    size_t counts_off = 256;
    size_t recs_off   = counts_off + (size_t)NCELL * sizeof(int);
    recs_off = (recs_off + 255) & ~(size_t)255;
    size_t total = recs_off + (size_t)NCELL * CAP * RECF * sizeof(float);

    int* mode = (int*)(ws + mode_off);

    if (ws_size >= total) {
        int*   counts = (int*)(ws + counts_off);
        float* recs   = (float*)(ws + recs_off);
        VEG_setup<<<PREPB, 256, 0, stream>>>((const unsigned char*)valid, xyz, sraw,
                                             rraw, wraw, vraw, recs, counts, mode, ng);
        VEG_splat<<<(npts + 255) / 256, 256, 0, stream>>>(x, recs, counts,
                                                          valid, mode, out, npts);
    } else {
        VEG_detect<<<1, 256, 0, stream>>>((const unsigned char*)valid, mode);
        VEG_brute<<<(npts + 255) / 256, 256, 0, stream>>>(x, xyz, sraw, rraw, wraw,
                                                          vraw, valid, mode, out,
                                                          npts, ng);
    }
}

// Round 8
// 112.241 us; speedup vs baseline: 1.1972x; 1.0697x over previous
//
#include <hip/hip_runtime.h>
#include <hip/hip_bf16.h>

namespace {

constexpr int GRIDC = 16;                    // 16^3 cells, cell = 0.0625 > max radius 0.0601
constexpr int NCELL = GRIDC * GRIDC * GRIDC; // 4096
constexpr int CAP   = 48;                    // per-cell list capacity (avg load ~5)
constexpr int PREPB = 8;                     // setup blocks; each owns NCELL/PREPB cells
constexpr int CPB   = NCELL / PREPB;         // 512 cells per block

__device__ __forceinline__ float sigmoid_(float v) {
    if (v >= 0.0f) { float e = expf(-v); return 1.0f / (1.0f + e); }
    float e = expf(v); return e / (1.0f + e);
}

// ---- setup: 8 blocks. Phase A: one thread per gaussian -> coalesced gdata
//      (12 floats: cx,cy,cz,a00, a11,a22,a01,a02, a12,w,wv,rad).
//      Phase B: each block owns 512 cells; recomputes only centers+radius for
//      all gaussians (cheap) and appends 4-B indices into its cells via LDS
//      counters (no global atomics, no pre-zero, no grid sync).
//      Block 0 also detects the bool-buffer layout: 0=uint8,1=int32,2=float32.
__global__ void __launch_bounds__(256)
VEG_setup(const unsigned char* __restrict__ vg,
          const float* __restrict__ xyz, const float* __restrict__ sraw,
          const float* __restrict__ rraw, const float* __restrict__ wraw,
          const float* __restrict__ vraw,
          float* __restrict__ gdata, int* __restrict__ lists,
          int* __restrict__ counts, int* __restrict__ mode_p, int ng) {
    __shared__ int scount[CPB];
    __shared__ int sf1, sf3;
    if (threadIdx.x == 0) { sf1 = 0; sf3 = 0; }
    for (int c = threadIdx.x; c < CPB; c += 256) scount[c] = 0;
    __syncthreads();

    if (blockIdx.x == 0) {
        uint4 v = ((const uint4*)vg)[threadIdx.x];       // 256*16 = 4096 B scanned
        unsigned m = v.x | v.y | v.z | v.w;
        if (m & 0x0000FF00u) atomicOr(&sf1, 1);          // byte%4==1 -> uint8 layout
        if (m & 0xFF000000u) atomicOr(&sf3, 1);          // byte%4==3 -> float32 (or uint8)
    }

    // ---- phase A: full preprocess, one thread per gaussian (no redundancy)
    int g0 = blockIdx.x * 256 + threadIdx.x;
    if (g0 < ng) {
        float s0 = expf(sraw[g0 * 3 + 0]);
        float s1 = expf(sraw[g0 * 3 + 1]);
        float s2 = expf(sraw[g0 * 3 + 2]);
        float r  = sqrtf(s0 * s0 + s1 * s1 + s2 * s2) + 1e-8f;
        float rs = 0.02f * tanhf(r / 0.02f);
        float fsc = rs / r;
        s0 *= fsc; s1 *= fsc; s2 *= fsc;

        float q0 = rraw[g0 * 4 + 0], q1 = rraw[g0 * 4 + 1];
        float q2 = rraw[g0 * 4 + 2], q3 = rraw[g0 * 4 + 3];
        float qn = fmaxf(sqrtf(q0 * q0 + q1 * q1 + q2 * q2 + q3 * q3), 1e-12f);
        float inv = 1.0f / qn;
        float rr = q0 * inv, qx = q1 * inv, qy = q2 * inv, qz = q3 * inv;
        float R00 = 1.0f - 2.0f * (qy * qy + qz * qz);
        float R01 = 2.0f * (qx * qy - rr * qz);
        float R02 = 2.0f * (qx * qz + rr * qy);
        float R10 = 2.0f * (qx * qy + rr * qz);
        float R11 = 1.0f - 2.0f * (qx * qx + qz * qz);
        float R12 = 2.0f * (qy * qz - rr * qx);
        float R20 = 2.0f * (qx * qz - rr * qy);
        float R21 = 2.0f * (qy * qz + rr * qx);
        float R22 = 1.0f - 2.0f * (qx * qx + qy * qy);

        float i0 = 1.0f / (s0 * s0), i1 = 1.0f / (s1 * s1), i2 = 1.0f / (s2 * s2);
        float w = sigmoid_(wraw[g0]);
        float v = sigmoid_(vraw[g0]);
        float rad = 3.0f * fmaxf(fmaxf(s0, s1), s2);     // qd<=9 => |d|<=3*max(s)
        rad = rad * 1.001f + 1e-6f;

        float* o = gdata + (size_t)g0 * 12;
        o[0]  = xyz[g0 * 3 + 0];
        o[1]  = xyz[g0 * 3 + 1];
        o[2]  = xyz[g0 * 3 + 2];
        o[3]  = R00 * R00 * i0 + R01 * R01 * i1 + R02 * R02 * i2;
        o[4]  = R10 * R10 * i0 + R11 * R11 * i1 + R12 * R12 * i2;
        o[5]  = R20 * R20 * i0 + R21 * R21 * i1 + R22 * R22 * i2;
        o[6]  = R00 * R10 * i0 + R01 * R11 * i1 + R02 * R12 * i2;
        o[7]  = R00 * R20 * i0 + R01 * R21 * i1 + R02 * R22 * i2;
        o[8]  = R10 * R20 * i0 + R11 * R21 * i1 + R12 * R22 * i2;
        o[9]  = w;
        o[10] = w * v;
        o[11] = rad;
    }

    // ---- phase B: slab-local index insertion (recompute only centers+radius)
    int cellbase = blockIdx.x * CPB;
    for (int g = threadIdx.x; g < ng; g += 256) {
        float s0 = expf(sraw[g * 3 + 0]);
        float s1 = expf(sraw[g * 3 + 1]);
        float s2 = expf(sraw[g * 3 + 2]);
        float r  = sqrtf(s0 * s0 + s1 * s1 + s2 * s2) + 1e-8f;
        float rs = 0.02f * tanhf(r / 0.02f);
        float fsc = rs / r;
        s0 *= fsc; s1 *= fsc; s2 *= fsc;
        float rad = 3.0f * fmaxf(fmaxf(s0, s1), s2);
        rad = rad * 1.001f + 1e-6f;

        float cx = xyz[g * 3 + 0], cy = xyz[g * 3 + 1], cz = xyz[g * 3 + 2];
        int xlo = max(0, (int)floorf((cx - rad) * (float)GRIDC));
        int xhi = min(GRIDC - 1, (int)floorf((cx + rad) * (float)GRIDC));
        int ylo = max(0, (int)floorf((cy - rad) * (float)GRIDC));
        int yhi = min(GRIDC - 1, (int)floorf((cy + rad) * (float)GRIDC));
        int zlo = max(0, (int)floorf((cz - rad) * (float)GRIDC));
        int zhi = min(GRIDC - 1, (int)floorf((cz + rad) * (float)GRIDC));
        int cmin = (zlo * GRIDC + ylo) * GRIDC + xlo;
        int cmax = (zhi * GRIDC + yhi) * GRIDC + xhi;
        if (cmax < cellbase || cmin >= cellbase + CPB) continue;

        for (int zz = zlo; zz <= zhi; ++zz)
            for (int yy = ylo; yy <= yhi; ++yy)
                for (int xx = xlo; xx <= xhi; ++xx) {
                    int cell  = (zz * GRIDC + yy) * GRIDC + xx;
                    int local = cell - cellbase;
                    if ((unsigned)local < (unsigned)CPB) {
                        int slot = atomicAdd(&scount[local], 1);
                        if (slot < CAP) lists[cell * CAP + slot] = g;
                    }
                }
    }
    __syncthreads();
    for (int c = threadIdx.x; c < CPB; c += 256) counts[cellbase + c] = scount[c];
    if (blockIdx.x == 0 && threadIdx.x == 0) *mode_p = sf1 ? 0 : (sf3 ? 2 : 1);
}

// ---- main: one thread per point; x staged via LDS; indexed gaussian records
__global__ void __launch_bounds__(256)
VEG_splat(const float* __restrict__ x, const float* __restrict__ gdata,
          const int* __restrict__ lists, const int* __restrict__ counts,
          const void* __restrict__ valid, const int* __restrict__ mode_p,
          float* __restrict__ out, int npts) {
    __shared__ float shx[768];
    int base = blockIdx.x * 256;
    int nrem = npts - base;
    if (nrem >= 256) {
        if (threadIdx.x < 192)
            ((float4*)shx)[threadIdx.x] = ((const float4*)(x + (size_t)base * 3))[threadIdx.x];
    } else {
        for (int j = threadIdx.x; j < nrem * 3; j += 256)
            shx[j] = x[(size_t)base * 3 + j];
    }
    __syncthreads();

    int i = base + threadIdx.x;
    if (i >= npts) return;

    float px = (shx[threadIdx.x * 3 + 0] + 1.0f) * 0.5f;
    float py = (shx[threadIdx.x * 3 + 1] + 1.0f) * 0.5f;
    float pz = (shx[threadIdx.x * 3 + 2] + 1.0f) * 0.5f;

    // issue the cell-count load first (longest dependent chain)
    int cx = min(GRIDC - 1, (int)(px * (float)GRIDC));
    int cy = min(GRIDC - 1, (int)(py * (float)GRIDC));
    int cz = min(GRIDC - 1, (int)(pz * (float)GRIDC));
    int cell = (cz * GRIDC + cy) * GRIDC + cx;
    int cnt = counts[cell];
    const int* lst = lists + cell * CAP;

    int ix = min(99, max(0, (int)rintf(px * 99.0f)));   // rintf = round half-to-even
    int iy = min(99, max(0, (int)rintf(py * 99.0f)));
    int iz = min(99, max(0, (int)rintf(pz * 99.0f)));
    int flat = iz * 10000 + iy * 100 + ix;

    int mode = *mode_p;
    bool vb;
    if (mode == 0)      vb = ((const unsigned char*)valid)[flat] != 0;
    else if (mode == 1) vb = ((const int*)valid)[flat] != 0;
    else                vb = ((const float*)valid)[flat] != 0.0f;

    cnt = (cnt < 0) ? 0 : min(cnt, CAP);
    float den = 0.0f, num = 0.0f;
#pragma unroll 2
    for (int j = 0; j < cnt; ++j) {
        int g = lst[j];
        const float4* gd = (const float4*)(gdata + (size_t)g * 12);
        float4 A = gd[0], B = gd[1], C = gd[2];
        float dx = px - A.x, dy = py - A.y, dz = pz - A.z;
        float qd = A.w * dx * dx + B.x * dy * dy + B.y * dz * dz +
                   2.0f * (B.z * dx * dy + B.w * dx * dz + C.x * dy * dz);
        if (qd <= 9.0f) {
            float e = __expf(-0.5f * qd);
            den = fmaf(C.y, e, den);
            num = fmaf(C.z, e, num);
        }
    }
    float y = (den > 0.0f) ? (num / den) : -1.0f;
    out[i] = vb ? y : 0.0f;
}

// ---- fallback: brute force (only if ws_size is absurdly small) ------------
__global__ void VEG_detect(const unsigned char* vg, int* mode) {
    __shared__ int f1, f3;
    if (threadIdx.x == 0) { f1 = 0; f3 = 0; }
    __syncthreads();
    for (int i = threadIdx.x; i < 4096; i += blockDim.x) {
        unsigned char b = vg[i];
        if (b) {
            int m = i & 3;
            if (m == 1) atomicOr(&f1, 1);
            if (m == 3) atomicOr(&f3, 1);
        }
    }
    __syncthreads();
    if (threadIdx.x == 0) *mode = f1 ? 0 : (f3 ? 2 : 1);
}

__global__ void __launch_bounds__(256)
VEG_brute(const float* __restrict__ x, const float* __restrict__ xyz,
          const float* __restrict__ sraw, const float* __restrict__ rraw,
          const float* __restrict__ wraw, const float* __restrict__ vraw,
          const void* __restrict__ valid, const int* __restrict__ mode_p,
          float* __restrict__ out, int npts, int ng) {
    __shared__ float sh[256 * 12];
    int i = blockIdx.x * blockDim.x + threadIdx.x;
    bool inb = i < npts;
    float px = 0, py = 0, pz = 0; int flat = 0;
    if (inb) {
        px = (x[i * 3 + 0] + 1.0f) * 0.5f;
        py = (x[i * 3 + 1] + 1.0f) * 0.5f;
        pz = (x[i * 3 + 2] + 1.0f) * 0.5f;
        int ix = min(99, max(0, (int)rintf(px * 99.0f)));
        int iy = min(99, max(0, (int)rintf(py * 99.0f)));
        int iz = min(99, max(0, (int)rintf(pz * 99.0f)));
        flat = iz * 10000 + iy * 100 + ix;
    }
    float den = 0.0f, num = 0.0f;
    for (int base = 0; base < ng; base += 256) {
        __syncthreads();
        int g = base + threadIdx.x;
        if (g < ng) {
            float s0 = expf(sraw[g * 3 + 0]);
            float s1 = expf(sraw[g * 3 + 1]);
            float s2 = expf(sraw[g * 3 + 2]);
            float r  = sqrtf(s0 * s0 + s1 * s1 + s2 * s2) + 1e-8f;
            float rs = 0.02f * tanhf(r / 0.02f);
            float fsc = rs / r;
            s0 *= fsc; s1 *= fsc; s2 *= fsc;
            float q0 = rraw[g * 4 + 0], q1 = rraw[g * 4 + 1];
            float q2 = rraw[g * 4 + 2], q3 = rraw[g * 4 + 3];
            float qn = fmaxf(sqrtf(q0 * q0 + q1 * q1 + q2 * q2 + q3 * q3), 1e-12f);
            float inv = 1.0f / qn;
            float rr = q0 * inv, qx = q1 * inv, qy = q2 * inv, qz = q3 * inv;
            float R00 = 1.0f - 2.0f * (qy * qy + qz * qz);
            float R01 = 2.0f * (qx * qy - rr * qz);
            float R02 = 2.0f * (qx * qz + rr * qy);
            float R10 = 2.0f * (qx * qy + rr * qz);
            float R11 = 1.0f - 2.0f * (qx * qx + qz * qz);
            float R12 = 2.0f * (qy * qz - rr * qx);
            float R20 = 2.0f * (qx * qz - rr * qy);
            float R21 = 2.0f * (qy * qz + rr * qx);
            float R22 = 1.0f - 2.0f * (qx * qx + qy * qy);
            float i0 = 1.0f / (s0 * s0), i1 = 1.0f / (s1 * s1), i2 = 1.0f / (s2 * s2);
            float* o = sh + threadIdx.x * 12;
            o[0] = xyz[g * 3 + 0]; o[1] = xyz[g * 3 + 1]; o[2] = xyz[g * 3 + 2];
            o[3] = R00 * R00 * i0 + R01 * R01 * i1 + R02 * R02 * i2;
            o[4] = R10 * R10 * i0 + R11 * R11 * i1 + R12 * R12 * i2;
            o[5] = R20 * R20 * i0 + R21 * R21 * i1 + R22 * R22 * i2;
            o[6] = R00 * R10 * i0 + R01 * R11 * i1 + R02 * R12 * i2;
            o[7] = R00 * R20 * i0 + R01 * R21 * i1 + R02 * R22 * i2;
            o[8] = R10 * R20 * i0 + R11 * R21 * i1 + R12 * R22 * i2;
            float w = sigmoid_(wraw[g]);
            float v = sigmoid_(vraw[g]);
            o[9] = w; o[10] = w * v; o[11] = 0.0f;
        }
        __syncthreads();
        int tile = min(256, ng - base);
        if (inb) {
            for (int j = 0; j < tile; ++j) {
                const float* o = sh + j * 12;
                float dx = px - o[0], dy = py - o[1], dz = pz - o[2];
                float qd = o[3] * dx * dx + o[4] * dy * dy + o[5] * dz * dz +
                           2.0f * (o[6] * dx * dy + o[7] * dx * dz + o[8] * dy * dz);
                if (qd <= 9.0f) {
                    float e = expf(-0.5f * qd);
                    den = fmaf(o[9], e, den);
                    num = fmaf(o[10], e, num);
                }
            }
        }
    }
    if (inb) {
        int mode = *mode_p;
        bool vb;
        if (mode == 0)      vb = ((const unsigned char*)valid)[flat] != 0;
        else if (mode == 1) vb = ((const int*)valid)[flat] != 0;
        else                vb = ((const float*)valid)[flat] != 0.0f;
        float y = (den > 0.0f) ? (num / den) : -1.0f;
        out[i] = vb ? y : 0.0f;
    }
}

} // namespace

extern "C" void kernel_launch(void* const* d_in, const int* in_sizes, int n_in,
                              void* d_out, int out_size, void* d_ws, size_t ws_size,
                              hipStream_t stream) {
    const float* x    = (const float*)d_in[0];
    const float* xyz  = (const float*)d_in[1];
    const float* sraw = (const float*)d_in[2];
    const float* rraw = (const float*)d_in[3];
    const float* wraw = (const float*)d_in[4];
    const float* vraw = (const float*)d_in[5];
    const void*  valid = d_in[6];
    float* out = (float*)d_out;

    int npts = in_sizes[0] / 3;
    int ng   = in_sizes[4];

    char* ws = (char*)d_ws;
    size_t mode_off   = 0;
    size_t counts_off = 256;
    size_t gdata_off  = counts_off + (size_t)NCELL * sizeof(int);
    gdata_off = (gdata_off + 255) & ~(size_t)255;
    size_t lists_off  = gdata_off + (size_t)ng * 12 * sizeof(float);
    lists_off = (lists_off + 255) & ~(size_t)255;
    size_t total = lists_off + (size_t)NCELL * CAP * sizeof(int);

    int* mode = (int*)(ws + mode_off);

    if (ws_size >= total && ng <= PREPB * 256) {
        int*   counts = (int*)(ws + counts_off);
        float* gdata  = (float*)(ws + gdata_off);
        int*   lists  = (int*)(ws + lists_off);
        VEG_setup<<<PREPB, 256, 0, stream>>>((const unsigned char*)valid, xyz, sraw,
                                             rraw, wraw, vraw, gdata, lists, counts,
                                             mode, ng);
        VEG_splat<<<(npts + 255) / 256, 256, 0, stream>>>(x, gdata, lists, counts,
                                                          valid, mode, out, npts);
    } else {
        VEG_detect<<<1, 256, 0, stream>>>((const unsigned char*)valid, mode);
        VEG_brute<<<(npts + 255) / 256, 256, 0, stream>>>(x, xyz, sraw, rraw, wraw,
                                                          vraw, valid, mode, out,
                                                          npts, ng);
    }
}